// Round 7
// baseline (184.451 us; speedup 1.0000x reference)
//
#include <hip/hip_runtime.h>

#define SLEN 1024
#define BATCH 2
#define DEPTH 6

typedef _Float16 h8 __attribute__((ext_vector_type(8)));
typedef float    f4 __attribute__((ext_vector_type(4)));
#define MF16(a, b, c) __builtin_amdgcn_mfma_f32_16x16x32_f16(a, b, c, 0, 0, 0)

// logical chunk <-> stored chunk swizzle (8 chunks of 8 halfs per 64-half row)
#define SW(row, c) (((c) ^ ((row) & 7)) * 8)

// async global->LDS, 16B per lane; LDS dest = wave-uniform base + lane*16
__device__ __forceinline__ void async_cp16(const _Float16* g, _Float16* l) {
  __builtin_amdgcn_global_load_lds(
      (const __attribute__((address_space(1))) void*)g,
      (__attribute__((address_space(3))) void*)l, 16, 0, 0);
}

// ---------------------------------------------------------------------------
// prep: bid 0..1023 x->fp16 ; 1024..2047 weight transpose+convert ;
//       2048..2303 mask bit-pack
// ---------------------------------------------------------------------------
__global__ __launch_bounds__(256) void prep(const float* __restrict__ x,
    const float* __restrict__ wq, const float* __restrict__ wk,
    const float* __restrict__ wv, const float* __restrict__ wo,
    const int* __restrict__ masks, _Float16* __restrict__ xh,
    _Float16* __restrict__ qt, _Float16* __restrict__ kt,
    _Float16* __restrict__ vt, _Float16* __restrict__ ot,
    unsigned int* __restrict__ mpk) {
  __shared__ _Float16 T[64][72];
  const int bid = blockIdx.x, t = threadIdx.x;
  if (bid < 1024) {
    int idx = (bid * 256 + t) * 8;
    float4 f0 = *(const float4*)(x + idx);
    float4 f1 = *(const float4*)(x + idx + 4);
    union { h8 v; _Float16 e[8]; } u;
    u.e[0] = (_Float16)f0.x; u.e[1] = (_Float16)f0.y;
    u.e[2] = (_Float16)f0.z; u.e[3] = (_Float16)f0.w;
    u.e[4] = (_Float16)f1.x; u.e[5] = (_Float16)f1.y;
    u.e[6] = (_Float16)f1.z; u.e[7] = (_Float16)f1.w;
    *(h8*)(xh + idx) = u.v;
  } else if (bid < 2048) {
    const int i = bid - 1024;
    const int wsel = i >> 8;
    const float* W = wsel == 0 ? wq : wsel == 1 ? wk : wsel == 2 ? wv : wo;
    _Float16* O = wsel == 0 ? qt : wsel == 1 ? kt : wsel == 2 ? vt : ot;
    const int k0 = ((i >> 4) & 15) * 64, n0 = (i & 15) * 64;
    const int rr = t >> 2, cs = (t & 3) * 16;
    #pragma unroll
    for (int j = 0; j < 4; ++j) {
      float4 f = *(const float4*)(W + (size_t)(k0 + rr) * 1024 + n0 + cs + j * 4);
      T[rr][cs + j * 4 + 0] = (_Float16)f.x;
      T[rr][cs + j * 4 + 1] = (_Float16)f.y;
      T[rr][cs + j * 4 + 2] = (_Float16)f.z;
      T[rr][cs + j * 4 + 3] = (_Float16)f.w;
    }
    __syncthreads();
    const int n = t >> 2, ks = (t & 3) * 16;
    union { h8 v; _Float16 e[8]; } u0, u1;
    #pragma unroll
    for (int j = 0; j < 8; ++j) { u0.e[j] = T[ks + j][n]; u1.e[j] = T[ks + 8 + j][n]; }
    *(h8*)(O + (size_t)(n0 + n) * 1024 + k0 + ks)     = u0.v;
    *(h8*)(O + (size_t)(n0 + n) * 1024 + k0 + ks + 8) = u1.v;
  } else {
    const int g = (bid - 2048) * 256 + t;
    const int row = g >> 5, w = g & 31;
    const int* m = masks + (size_t)row * 1024 + w * 32;
    unsigned int bits = 0;
    #pragma unroll
    for (int j4 = 0; j4 < 8; ++j4) {
      int4 mm = *(const int4*)(m + j4 * 4);
      if (mm.x) bits |= 1u << (j4 * 4 + 0);
      if (mm.y) bits |= 1u << (j4 * 4 + 1);
      if (mm.z) bits |= 1u << (j4 * 4 + 2);
      if (mm.w) bits |= 1u << (j4 * 4 + 3);
    }
    mpk[g] = bits;
  }
}

// ---------------------------------------------------------------------------
// fp16 MFMA GEMM, async-LDS staged, 128x128 tile BK=64.
// TMODE 0: plain store (CT float or fp16).
// TMODE 1: V transposed-per-batch store: C[(m>>10)*1024 + n][m&1023]
// TMODE 2: fused RoPE epilogue (Q/K): acc -> LDS -> per-(row,head) rotate -> fp16
// ---------------------------------------------------------------------------
template <int TMODE, typename CT>
__device__ __forceinline__ void gemm16(const _Float16* __restrict__ A,
                                       const _Float16* __restrict__ Bt,
                                       CT* __restrict__ C,
                                       const int* __restrict__ Hm,
                                       const int* __restrict__ Bm,
                                       const float* __restrict__ fc,
                                       const float* __restrict__ fs) {
  __shared__ _Float16 SH[16384];     // As = SH[0:8192), Bs = SH[8192:)
  __shared__ float FR[128];          // c1|s1|c2|s2 (TMODE2)
  _Float16* As = SH;
  _Float16* Bs = SH + 8192;
  const int t    = threadIdx.x;
  const int bm   = blockIdx.y * 128, bn = blockIdx.x * 128;
  const int w    = t >> 6, lane = t & 63;
  const int ln15 = lane & 15, quad = lane >> 4;
  const int wm   = (w >> 1) * 64, wn = (w & 1) * 64;

  if (TMODE == 2 && t < 128) {
    int g = t & 31;
    FR[t] = (t < 32) ? fc[32 + g] : (t < 64) ? fs[32 + g]
          : (t < 96) ? fc[64 + g] : fs[64 + g];
  }

  const int srow8 = lane >> 3;
  const int sch   = (lane & 7) ^ srow8;
  const _Float16* agp = A  + (size_t)(bm + w * 32 + srow8) * 1024 + sch * 8;
  const _Float16* bgp = Bt + (size_t)(bn + w * 32 + srow8) * 1024 + sch * 8;
  _Float16* alds = As + w * 2048;
  _Float16* blds = Bs + w * 2048;

  f4 acc[4][4];
  #pragma unroll
  for (int i = 0; i < 4; ++i)
    #pragma unroll
    for (int j = 0; j < 4; ++j) acc[i][j] = (f4){0.f, 0.f, 0.f, 0.f};

  for (int k0 = 0; k0 < 1024; k0 += 64) {
    #pragma unroll
    for (int j = 0; j < 4; ++j) {
      async_cp16(agp + k0 + j * 8192, alds + j * 512);
      async_cp16(bgp + k0 + j * 8192, blds + j * 512);
    }
    __syncthreads();
    #pragma unroll
    for (int kk8 = 0; kk8 < 8; kk8 += 4) {
      h8 af[4], bf[4];
      #pragma unroll
      for (int i = 0; i < 4; ++i) {
        int row = wm + i * 16 + ln15;
        af[i] = *(const h8*)&As[row * 64 + SW(row, kk8 + quad)];
      }
      #pragma unroll
      for (int j = 0; j < 4; ++j) {
        int row = wn + j * 16 + ln15;
        bf[j] = *(const h8*)&Bs[row * 64 + SW(row, kk8 + quad)];
      }
      #pragma unroll
      for (int i = 0; i < 4; ++i)
        #pragma unroll
        for (int j = 0; j < 4; ++j)
          acc[i][j] = MF16(af[i], bf[j], acc[i][j]);
    }
    __syncthreads();
  }

  if (TMODE == 0) {
    #pragma unroll
    for (int i = 0; i < 4; ++i) {
      int row = bm + wm + i * 16 + quad * 4;
      #pragma unroll
      for (int r = 0; r < 4; ++r)
        #pragma unroll
        for (int j = 0; j < 4; ++j)
          C[(size_t)(row + r) * 1024 + bn + wn + j * 16 + ln15] = (CT)acc[i][j][r];
    }
  } else if (TMODE == 1) {
    #pragma unroll
    for (int i = 0; i < 4; ++i) {
      int m0 = bm + wm + i * 16 + quad * 4;
      #pragma unroll
      for (int r = 0; r < 4; ++r) {
        int m = m0 + r;
        size_t base = ((size_t)(m >> 10) * 1024) * 1024 + (m & 1023);
        #pragma unroll
        for (int j = 0; j < 4; ++j)
          C[base + (size_t)(bn + wn + j * 16 + ln15) * 1024] = (CT)acc[i][j][r];
      }
    }
  } else {
    // ---- fused RoPE epilogue ----
    // acc -> SH as [128][128] fp16, 16B-chunk XOR swizzled per row
    #pragma unroll
    for (int i = 0; i < 4; ++i)
      #pragma unroll
      for (int j = 0; j < 4; ++j) {
        int cl = wn + j * 16 + ln15;
        #pragma unroll
        for (int r = 0; r < 4; ++r) {
          int rl = wm + i * 16 + quad * 4 + r;
          SH[rl * 128 + (((cl >> 3) ^ (rl & 15)) << 3) + (cl & 7)] =
              (_Float16)acc[i][j][r];
        }
      }
    __syncthreads();
    // one thread per (row, head): full 64-dim head vector
    const int row = t >> 1, head = t & 1;
    const int bs = bm + row;              // b*1024 + s (tiles don't straddle batch)
    float vv[64];
    #pragma unroll
    for (int cc = 0; cc < 8; ++cc) {
      int phys = (head * 8 + cc) ^ (row & 15);
      union { h8 v; _Float16 e[8]; } u;
      u.v = *(const h8*)&SH[row * 128 + phys * 8];
      #pragma unroll
      for (int e = 0; e < 8; ++e) vv[cc * 8 + e] = (float)u.e[e];
    }
    #pragma unroll 1
    for (int d = 0; d < DEPTH; ++d) {
      if (Hm[d * (BATCH * SLEN) + bs] != 0) {
        #pragma unroll
        for (int j = 0; j < 32; ++j) {
          float re = vv[2 * j], im = vv[2 * j + 1];
          vv[2 * j]     = re * FR[j] - im * FR[32 + j];
          vv[2 * j + 1] = re * FR[32 + j] + im * FR[j];
        }
      }
      if (Bm[(d * 2 + 0) * (BATCH * SLEN) + bs] != 0) {
        #pragma unroll
        for (int j = 0; j < 32; ++j) {
          float re = vv[j], im = vv[j + 32];
          vv[j]      = re * FR[j] - im * FR[32 + j];
          vv[j + 32] = re * FR[32 + j] + im * FR[j];
        }
      }
      if (Bm[(d * 2 + 1) * (BATCH * SLEN) + bs] != 0) {
        #pragma unroll
        for (int j = 0; j < 32; ++j) {
          float re = vv[j], im = vv[j + 32];
          vv[j]      = re * FR[64 + j] - im * FR[96 + j];
          vv[j + 32] = re * FR[96 + j] + im * FR[64 + j];
        }
      }
    }
    _Float16* dst = (_Float16*)C + (size_t)(bm + row) * 1024 + bn + head * 64;
    #pragma unroll
    for (int cc = 0; cc < 8; ++cc) {
      union { h8 v; _Float16 e[8]; } u;
      #pragma unroll
      for (int e = 0; e < 8; ++e) u.e[e] = (_Float16)vv[cc * 8 + e];
      *(h8*)(dst + cc * 8) = u.v;
    }
  }
}

__global__ __launch_bounds__(256) void gemm_qkv16(const _Float16* __restrict__ xh,
    const _Float16* __restrict__ qt, const _Float16* __restrict__ kt,
    const _Float16* __restrict__ vtw, _Float16* __restrict__ q,
    _Float16* __restrict__ k, _Float16* __restrict__ vth,
    const int* __restrict__ Hm, const int* __restrict__ Bm,
    const float* __restrict__ fc, const float* __restrict__ fs) {
  if (blockIdx.z == 2)
    gemm16<1, _Float16>(xh, vtw, vth, nullptr, nullptr, nullptr, nullptr);
  else if (blockIdx.z == 1)
    gemm16<2, _Float16>(xh, kt, k, Hm, Bm, fc, fs);
  else
    gemm16<2, _Float16>(xh, qt, q, Hm, Bm, fc, fs);
}

__global__ __launch_bounds__(256) void gemm_o16(const _Float16* __restrict__ A,
    const _Float16* __restrict__ Bt, float* __restrict__ C) {
  gemm16<0, float>(A, Bt, C, nullptr, nullptr, nullptr, nullptr);
}

// ---------------------------------------------------------------------------
// MFMA flash attention, double-buffered async staging, ONE barrier per chunk:
//   barrier; [issue stage(c+1) async]; compute(c); -> next barrier drains it,
//   so the c+1 loads overlap all of compute(c).
// Bitpacked mask (preloaded a chunk ahead); fixed-shift softmax p=exp(s/8-3).
// ---------------------------------------------------------------------------
__global__ __launch_bounds__(256) void attn_mfma(const _Float16* __restrict__ qh,
    const _Float16* __restrict__ kh, const _Float16* __restrict__ vth,
    const unsigned int* __restrict__ mpk, _Float16* __restrict__ out) {
  __shared__ _Float16 Ks[2][64 * 64];
  __shared__ _Float16 Vs[2][64 * 64];
  __shared__ _Float16 QP[4][16][72];

  const int t    = threadIdx.x;
  const int w    = t >> 6, lane = t & 63;
  const int ln15 = lane & 15, quad = lane >> 4;

  const int bh = blockIdx.x & 31;       // same (b,h) -> same XCD
  const int s0 = (blockIdx.x >> 5) * 64;
  const int b = bh >> 4, h = bh & 15;
  const size_t qkbase = (size_t)b * (SLEN * 1024) + h * 64;
  const size_t vbase  = ((size_t)b * 1024 + h * 64) * SLEN;

  // ---- stage Q (wave-aligned; no barrier) ----
  {
    const int srow = t >> 2, sc0 = (t & 3) * 16;
    const _Float16* src = qh + qkbase + (size_t)(s0 + srow) * 1024 + sc0;
    *(h8*)&QP[w][srow & 15][sc0]     = *(const h8*)src;
    *(h8*)&QP[w][srow & 15][sc0 + 8] = *(const h8*)(src + 8);
  }
  h8 aq0 = *(h8*)&QP[w][ln15][quad * 8];
  h8 aq1 = *(h8*)&QP[w][ln15][32 + quad * 8];

  const int srow8 = lane >> 3;
  const int sch   = (lane & 7) ^ srow8;
  const _Float16* kgp = kh + qkbase + (size_t)(w * 16 + srow8) * 1024 + sch * 8;
  const _Float16* vgp = vth + vbase + (size_t)(w * 16 + srow8) * 1024 + sch * 8;

  const unsigned int* mp = mpk + ((size_t)b * SLEN + s0 + w * 16 + quad * 4) * 32;

  float lrow[4] = {1e-30f, 1e-30f, 1e-30f, 1e-30f};
  f4 oacc[4];
  #pragma unroll
  for (int f = 0; f < 4; ++f) oacc[f] = (f4){0.f, 0.f, 0.f, 0.f};

  // prologue: stage chunk 0 into buf 0; preload chunk-0 mask words
  async_cp16(kgp,        &Ks[0][w * 1024]);
  async_cp16(kgp + 8192, &Ks[0][w * 1024 + 512]);
  async_cp16(vgp,        &Vs[0][w * 1024]);
  async_cp16(vgp + 8192, &Vs[0][w * 1024 + 512]);
  unsigned int w0[4], w1[4];
  #pragma unroll
  for (int r = 0; r < 4; ++r) { w0[r] = mp[r * 32]; w1[r] = mp[r * 32 + 1]; }
  __syncthreads();

  for (int c = 0; c < 16; ++c) {
    const int cur = c & 1;
    unsigned int nw0[4], nw1[4];
    if (c < 15) {
      // issue next-chunk staging (lands during compute; drained at end barrier)
      const size_t ko = (size_t)((c + 1) * 64) * 1024;
      const int    vo = (c + 1) * 64;
      async_cp16(kgp + ko,        &Ks[cur ^ 1][w * 1024]);
      async_cp16(kgp + ko + 8192, &Ks[cur ^ 1][w * 1024 + 512]);
      async_cp16(vgp + vo,        &Vs[cur ^ 1][w * 1024]);
      async_cp16(vgp + vo + 8192, &Vs[cur ^ 1][w * 1024 + 512]);
      #pragma unroll
      for (int r = 0; r < 4; ++r) {
        nw0[r] = mp[r * 32 + (c + 1) * 2];
        nw1[r] = mp[r * 32 + (c + 1) * 2 + 1];
      }
    }

    // ---- S = Q K^T ----
    f4 s[4];
    #pragma unroll
    for (int f = 0; f < 4; ++f) {
      int row = f * 16 + ln15;
      h8 bk0 = *(const h8*)&Ks[cur][row * 64 + SW(row, quad)];
      h8 bk1 = *(const h8*)&Ks[cur][row * 64 + SW(row, 4 + quad)];
      f4 acc = (f4){0.f, 0.f, 0.f, 0.f};
      acc = MF16(aq0, bk0, acc);
      acc = MF16(aq1, bk1, acc);
      s[f] = acc;
    }
    // ---- masked exp, P store, l accumulate ----
    #pragma unroll
    for (int f = 0; f < 4; ++f) {
      const int col = f * 16 + ln15;
      #pragma unroll
      for (int r = 0; r < 4; ++r) {
        unsigned int wd = (col & 32) ? w1[r] : w0[r];
        float p = ((wd >> (col & 31)) & 1u)
                    ? __expf(s[f][r] * 0.125f - 3.0f) : 0.0f;
        lrow[r] += p;
        QP[w][quad * 4 + r][col] = (_Float16)p;
      }
    }
    // ---- O += P V ----
    h8 ap0 = *(h8*)&QP[w][ln15][quad * 8];
    h8 ap1 = *(h8*)&QP[w][ln15][32 + quad * 8];
    #pragma unroll
    for (int f = 0; f < 4; ++f) {
      int row = f * 16 + ln15;
      h8 bv0 = *(const h8*)&Vs[cur][row * 64 + SW(row, quad)];
      h8 bv1 = *(const h8*)&Vs[cur][row * 64 + SW(row, 4 + quad)];
      f4 o = oacc[f];
      o = MF16(ap0, bv0, o);
      o = MF16(ap1, bv1, o);
      oacc[f] = o;
    }
    if (c < 15) {
      #pragma unroll
      for (int r = 0; r < 4; ++r) { w0[r] = nw0[r]; w1[r] = nw1[r]; }
    }
    __syncthreads();   // compute done + next stage drained
  }

  // ---- final l reduction ----
  #pragma unroll
  for (int r = 0; r < 4; ++r) {
    float sm = lrow[r];
    sm += __shfl_xor(sm, 1);
    sm += __shfl_xor(sm, 2);
    sm += __shfl_xor(sm, 4);
    sm += __shfl_xor(sm, 8);
    lrow[r] = 1.0f / sm;
  }
  // ---- repack via wave-private LDS, 16B stores ----
  #pragma unroll
  for (int f = 0; f < 4; ++f)
    #pragma unroll
    for (int r = 0; r < 4; ++r)
      QP[w][quad * 4 + r][f * 16 + ln15] = (_Float16)(oacc[f][r] * lrow[r]);
  const int orow = lane >> 2, oseg = (lane & 3) * 16;
  _Float16* op = out + qkbase + (size_t)(s0 + w * 16 + orow) * 1024 + oseg;
  *(h8*)op       = *(h8*)&QP[w][orow][oseg];
  *(h8*)(op + 8) = *(h8*)&QP[w][orow][oseg + 8];
}

// ---------------------------------------------------------------------------
extern "C" void kernel_launch(void* const* d_in, const int* in_sizes, int n_in,
                              void* d_out, int out_size, void* d_ws, size_t ws_size,
                              hipStream_t stream) {
  const float* x     = (const float*)d_in[0];
  const int*   masks = (const int*)d_in[1];
  const int*   Hm    = (const int*)d_in[2];
  const int*   Bm    = (const int*)d_in[3];
  const float* fc    = (const float*)d_in[4];
  const float* fs    = (const float*)d_in[5];
  const float* wq    = (const float*)d_in[6];
  const float* wk    = (const float*)d_in[7];
  const float* wv    = (const float*)d_in[8];
  const float* wo    = (const float*)d_in[9];
  float* out = (float*)d_out;

  _Float16* xh   = (_Float16*)d_ws;          // 2M halfs
  _Float16* wqt  = xh + (1 << 21);           // 1M each
  _Float16* wkt  = wqt + (1 << 20);
  _Float16* wvt  = wkt + (1 << 20);
  _Float16* wot  = wvt + (1 << 20);
  _Float16* qhh  = wot + (1 << 20);          // 2M
  _Float16* khh  = qhh + (1 << 21);          // 2M
  _Float16* vth  = khh + (1 << 21);          // 2M
  _Float16* aoh  = vth + (1 << 21);          // 2M
  unsigned int* mpk = (unsigned int*)(aoh + (1 << 21));  // 64K words

  dim3 blk(256);
  prep<<<dim3(2304), blk, 0, stream>>>(x, wq, wk, wv, wo, masks,
                                       xh, wqt, wkt, wvt, wot, mpk);
  gemm_qkv16<<<dim3(8, 16, 3), blk, 0, stream>>>(xh, wqt, wkt, wvt, qhh, khh,
                                                 vth, Hm, Bm, fc, fs);
  attn_mfma<<<dim3(512), blk, 0, stream>>>(qhh, khh, vth, mpk, aoh);
  gemm_o16<<<dim3(8, 16), blk, 0, stream>>>(aoh, wot, out);
}

// Round 9
// 166.487 us; speedup vs baseline: 1.1079x; 1.1079x over previous
//
#include <hip/hip_runtime.h>

#define SLEN 1024
#define BATCH 2
#define DEPTH 6

typedef _Float16 h8 __attribute__((ext_vector_type(8)));
typedef float    f4 __attribute__((ext_vector_type(4)));
#define MF16(a, b, c) __builtin_amdgcn_mfma_f32_16x16x32_f16(a, b, c, 0, 0, 0)

// logical chunk <-> stored chunk swizzle (8 chunks of 8 halfs per 64-half row)
#define SW(row, c) ((((c) ^ ((row) & 7))) * 8)

// async global->LDS, 16B per lane; LDS dest = wave-uniform base + lane*16
__device__ __forceinline__ void async_cp16(const _Float16* g, _Float16* l) {
  __builtin_amdgcn_global_load_lds(
      (const __attribute__((address_space(1))) void*)g,
      (__attribute__((address_space(3))) void*)l, 16, 0, 0);
}

// ---------------------------------------------------------------------------
// prep: bid 0..1023 x->fp16 ; 1024..2047 weight transpose+convert ;
//       2048..2303 mask bit-pack
// ---------------------------------------------------------------------------
__global__ __launch_bounds__(256) void prep(const float* __restrict__ x,
    const float* __restrict__ wq, const float* __restrict__ wk,
    const float* __restrict__ wv, const float* __restrict__ wo,
    const int* __restrict__ masks, _Float16* __restrict__ xh,
    _Float16* __restrict__ qt, _Float16* __restrict__ kt,
    _Float16* __restrict__ vt, _Float16* __restrict__ ot,
    unsigned int* __restrict__ mpk) {
  __shared__ _Float16 T[64][72];
  const int bid = blockIdx.x, t = threadIdx.x;
  if (bid < 1024) {
    int idx = (bid * 256 + t) * 8;
    float4 f0 = *(const float4*)(x + idx);
    float4 f1 = *(const float4*)(x + idx + 4);
    union { h8 v; _Float16 e[8]; } u;
    u.e[0] = (_Float16)f0.x; u.e[1] = (_Float16)f0.y;
    u.e[2] = (_Float16)f0.z; u.e[3] = (_Float16)f0.w;
    u.e[4] = (_Float16)f1.x; u.e[5] = (_Float16)f1.y;
    u.e[6] = (_Float16)f1.z; u.e[7] = (_Float16)f1.w;
    *(h8*)(xh + idx) = u.v;
  } else if (bid < 2048) {
    const int i = bid - 1024;
    const int wsel = i >> 8;
    const float* W = wsel == 0 ? wq : wsel == 1 ? wk : wsel == 2 ? wv : wo;
    _Float16* O = wsel == 0 ? qt : wsel == 1 ? kt : wsel == 2 ? vt : ot;
    const int k0 = ((i >> 4) & 15) * 64, n0 = (i & 15) * 64;
    const int rr = t >> 2, cs = (t & 3) * 16;
    #pragma unroll
    for (int j = 0; j < 4; ++j) {
      float4 f = *(const float4*)(W + (size_t)(k0 + rr) * 1024 + n0 + cs + j * 4);
      T[rr][cs + j * 4 + 0] = (_Float16)f.x;
      T[rr][cs + j * 4 + 1] = (_Float16)f.y;
      T[rr][cs + j * 4 + 2] = (_Float16)f.z;
      T[rr][cs + j * 4 + 3] = (_Float16)f.w;
    }
    __syncthreads();
    const int n = t >> 2, ks = (t & 3) * 16;
    union { h8 v; _Float16 e[8]; } u0, u1;
    #pragma unroll
    for (int j = 0; j < 8; ++j) { u0.e[j] = T[ks + j][n]; u1.e[j] = T[ks + 8 + j][n]; }
    *(h8*)(O + (size_t)(n0 + n) * 1024 + k0 + ks)     = u0.v;
    *(h8*)(O + (size_t)(n0 + n) * 1024 + k0 + ks + 8) = u1.v;
  } else {
    const int g = (bid - 2048) * 256 + t;
    const int row = g >> 5, w = g & 31;
    const int* m = masks + (size_t)row * 1024 + w * 32;
    unsigned int bits = 0;
    #pragma unroll
    for (int j4 = 0; j4 < 8; ++j4) {
      int4 mm = *(const int4*)(m + j4 * 4);
      if (mm.x) bits |= 1u << (j4 * 4 + 0);
      if (mm.y) bits |= 1u << (j4 * 4 + 1);
      if (mm.z) bits |= 1u << (j4 * 4 + 2);
      if (mm.w) bits |= 1u << (j4 * 4 + 3);
    }
    mpk[g] = bits;
  }
}

// ---------------------------------------------------------------------------
// fp16 MFMA GEMM, 64x128 tile, BK=64, SINGLE-buffer async-LDS staging,
// 2 barriers per K-chunk (proven r6/r7 structure). SH passed in (24.5 KB).
// Wave-tile 32x64 (acc 2x4). TMODE 0: plain store. TMODE 1: V-transpose.
// ---------------------------------------------------------------------------
template <int TMODE, typename CT>
__device__ __forceinline__ void gemm16(const _Float16* __restrict__ A,
                                       const _Float16* __restrict__ Bt,
                                       CT* __restrict__ C,
                                       _Float16* __restrict__ SH) {
  _Float16* As = SH;            // 4096 halfs: 64 rows x 64
  _Float16* Bs = SH + 4096;     // 8192 halfs: 128 rows x 64
  const int t    = threadIdx.x;
  const int bm   = blockIdx.y * 64, bn = blockIdx.x * 128;
  const int w    = t >> 6, lane = t & 63;
  const int ln15 = lane & 15, quad = lane >> 4;
  const int wm   = (w >> 1) * 32, wn = (w & 1) * 64;

  // staging lane map: 8 rows x 8 chunks per issue; row&7 == lane>>3
  const int srow8 = lane >> 3;
  const int sch   = (lane & 7) ^ srow8;
  const _Float16* agp = A  + (size_t)(bm + w * 16 + srow8) * 1024 + sch * 8;
  const _Float16* bgp = Bt + (size_t)(bn + w * 32 + srow8) * 1024 + sch * 8;

  f4 acc[2][4];
  #pragma unroll
  for (int i = 0; i < 2; ++i)
    #pragma unroll
    for (int j = 0; j < 4; ++j) acc[i][j] = (f4){0.f, 0.f, 0.f, 0.f};

  for (int k0 = 0; k0 < 1024; k0 += 64) {
    // wave w stages A rows [w*16, w*16+16), B rows [w*32, w*32+32)
    #pragma unroll
    for (int j = 0; j < 2; ++j)
      async_cp16(agp + k0 + j * 8192, As + w * 1024 + j * 512);
    #pragma unroll
    for (int j = 0; j < 4; ++j)
      async_cp16(bgp + k0 + j * 8192, Bs + w * 2048 + j * 512);
    __syncthreads();   // drain async stage + all waves ready
    #pragma unroll
    for (int kk = 0; kk < 8; kk += 4) {
      h8 af[2], bf[4];
      #pragma unroll
      for (int i = 0; i < 2; ++i) {
        int row = wm + i * 16 + ln15;
        af[i] = *(const h8*)&As[row * 64 + SW(row, kk + quad)];
      }
      #pragma unroll
      for (int j = 0; j < 4; ++j) {
        int row = wn + j * 16 + ln15;
        bf[j] = *(const h8*)&Bs[row * 64 + SW(row, kk + quad)];
      }
      #pragma unroll
      for (int i = 0; i < 2; ++i)
        #pragma unroll
        for (int j = 0; j < 4; ++j)
          acc[i][j] = MF16(af[i], bf[j], acc[i][j]);
    }
    __syncthreads();   // all reads done before next chunk overwrites
  }

  if (TMODE == 0) {
    #pragma unroll
    for (int i = 0; i < 2; ++i) {
      int row = bm + wm + i * 16 + quad * 4;
      #pragma unroll
      for (int r = 0; r < 4; ++r)
        #pragma unroll
        for (int j = 0; j < 4; ++j)
          C[(size_t)(row + r) * 1024 + bn + wn + j * 16 + ln15] = (CT)acc[i][j][r];
    }
  } else {
    #pragma unroll
    for (int i = 0; i < 2; ++i) {
      int m0 = bm + wm + i * 16 + quad * 4;
      #pragma unroll
      for (int r = 0; r < 4; ++r) {
        int m = m0 + r;
        size_t base = ((size_t)(m >> 10) * 1024) * 1024 + (m & 1023);
        #pragma unroll
        for (int j = 0; j < 4; ++j)
          C[base + (size_t)(bn + wn + j * 16 + ln15) * 1024] = (CT)acc[i][j][r];
      }
    }
  }
}

__global__ __launch_bounds__(256) void gemm_qkv16(
    const _Float16* __restrict__ xh, const _Float16* __restrict__ qt,
    const _Float16* __restrict__ kt, const _Float16* __restrict__ vtw,
    _Float16* __restrict__ q, _Float16* __restrict__ k,
    _Float16* __restrict__ vth) {
  __shared__ _Float16 SH[12288];
  if (blockIdx.z == 2)      gemm16<1, _Float16>(xh, vtw, vth, SH);
  else if (blockIdx.z == 1) gemm16<0, _Float16>(xh, kt, k, SH);
  else                      gemm16<0, _Float16>(xh, qt, q, SH);
}

__global__ __launch_bounds__(256) void gemm_o16(
    const _Float16* __restrict__ A, const _Float16* __restrict__ Bt,
    float* __restrict__ C) {
  __shared__ _Float16 SH[12288];
  gemm16<0, float>(A, Bt, C, SH);
}

// ---------------------------------------------------------------------------
// RoPE: fp16 in/out (in place), fp32 math.  (round-6 proven version)
// ---------------------------------------------------------------------------
__global__ __launch_bounds__(256) void rope_kernel(_Float16* __restrict__ qf,
    _Float16* __restrict__ kf, const int* __restrict__ Hm,
    const int* __restrict__ Bm, const float* __restrict__ fc,
    const float* __restrict__ fs) {
  __shared__ float c1[32], s1[32], c2[32], s2[32];
  const int t = threadIdx.x;
  if (t < 32) {
    c1[t] = fc[32 + t]; s1[t] = fs[32 + t];
    c2[t] = fc[64 + t]; s2[t] = fs[64 + t];
  }
  __syncthreads();
  const int gid = blockIdx.x * 256 + t;
  const int bs  = gid >> 4;
  _Float16* base = (blockIdx.y == 0 ? qf : kf) + (size_t)gid * 64;
  float vv[64];
  #pragma unroll
  for (int i = 0; i < 8; ++i) {
    union { h8 v; _Float16 e[8]; } u;
    u.v = *(const h8*)(base + i * 8);
    #pragma unroll
    for (int j = 0; j < 8; ++j) vv[i * 8 + j] = (float)u.e[j];
  }
  #pragma unroll 1
  for (int d = 0; d < DEPTH; ++d) {
    if (Hm[d * (BATCH * SLEN) + bs] != 0) {
      #pragma unroll
      for (int j = 0; j < 32; ++j) {
        float re = vv[2 * j], im = vv[2 * j + 1];
        vv[2 * j]     = re * c1[j] - im * s1[j];
        vv[2 * j + 1] = re * s1[j] + im * c1[j];
      }
    }
    if (Bm[(d * 2 + 0) * (BATCH * SLEN) + bs] != 0) {
      #pragma unroll
      for (int j = 0; j < 32; ++j) {
        float re = vv[j], im = vv[j + 32];
        vv[j]      = re * c1[j] - im * s1[j];
        vv[j + 32] = re * s1[j] + im * c1[j];
      }
    }
    if (Bm[(d * 2 + 1) * (BATCH * SLEN) + bs] != 0) {
      #pragma unroll
      for (int j = 0; j < 32; ++j) {
        float re = vv[j], im = vv[j + 32];
        vv[j]      = re * c2[j] - im * s2[j];
        vv[j + 32] = re * s2[j] + im * c2[j];
      }
    }
  }
  #pragma unroll
  for (int i = 0; i < 8; ++i) {
    union { h8 v; _Float16 e[8]; } u;
    #pragma unroll
    for (int j = 0; j < 8; ++j) u.e[j] = (_Float16)vv[i * 8 + j];
    *(h8*)(base + i * 8) = u.v;
  }
}

// ---------------------------------------------------------------------------
// MFMA flash attention, double-buffered async staging, one barrier per chunk.
// Bitpacked mask (preloaded a chunk ahead); fixed-shift softmax p=exp(s/8-3).
// (round-6/7 proven version, unchanged)
// ---------------------------------------------------------------------------
__global__ __launch_bounds__(256) void attn_mfma(const _Float16* __restrict__ qh,
    const _Float16* __restrict__ kh, const _Float16* __restrict__ vth,
    const unsigned int* __restrict__ mpk, _Float16* __restrict__ out) {
  __shared__ _Float16 Ks[2][64 * 64];
  __shared__ _Float16 Vs[2][64 * 64];
  __shared__ _Float16 QP[4][16][72];

  const int t    = threadIdx.x;
  const int w    = t >> 6, lane = t & 63;
  const int ln15 = lane & 15, quad = lane >> 4;

  const int bh = blockIdx.x & 31;       // same (b,h) -> same XCD
  const int s0 = (blockIdx.x >> 5) * 64;
  const int b = bh >> 4, h = bh & 15;
  const size_t qkbase = (size_t)b * (SLEN * 1024) + h * 64;
  const size_t vbase  = ((size_t)b * 1024 + h * 64) * SLEN;

  {
    const int srow = t >> 2, sc0 = (t & 3) * 16;
    const _Float16* src = qh + qkbase + (size_t)(s0 + srow) * 1024 + sc0;
    *(h8*)&QP[w][srow & 15][sc0]     = *(const h8*)src;
    *(h8*)&QP[w][srow & 15][sc0 + 8] = *(const h8*)(src + 8);
  }
  h8 aq0 = *(h8*)&QP[w][ln15][quad * 8];
  h8 aq1 = *(h8*)&QP[w][ln15][32 + quad * 8];

  const int srow8 = lane >> 3;
  const int sch   = (lane & 7) ^ srow8;
  const _Float16* kgp = kh + qkbase + (size_t)(w * 16 + srow8) * 1024 + sch * 8;
  const _Float16* vgp = vth + vbase + (size_t)(w * 16 + srow8) * 1024 + sch * 8;

  const unsigned int* mp = mpk + ((size_t)b * SLEN + s0 + w * 16 + quad * 4) * 32;

  float lrow[4] = {1e-30f, 1e-30f, 1e-30f, 1e-30f};
  f4 oacc[4];
  #pragma unroll
  for (int f = 0; f < 4; ++f) oacc[f] = (f4){0.f, 0.f, 0.f, 0.f};

  async_cp16(kgp,        &Ks[0][w * 1024]);
  async_cp16(kgp + 8192, &Ks[0][w * 1024 + 512]);
  async_cp16(vgp,        &Vs[0][w * 1024]);
  async_cp16(vgp + 8192, &Vs[0][w * 1024 + 512]);
  unsigned int w0[4], w1[4];
  #pragma unroll
  for (int r = 0; r < 4; ++r) { w0[r] = mp[r * 32]; w1[r] = mp[r * 32 + 1]; }
  __syncthreads();

  for (int c = 0; c < 16; ++c) {
    const int cur = c & 1;
    unsigned int nw0[4], nw1[4];
    if (c < 15) {
      const size_t ko = (size_t)((c + 1) * 64) * 1024;
      const int    vo = (c + 1) * 64;
      async_cp16(kgp + ko,        &Ks[cur ^ 1][w * 1024]);
      async_cp16(kgp + ko + 8192, &Ks[cur ^ 1][w * 1024 + 512]);
      async_cp16(vgp + vo,        &Vs[cur ^ 1][w * 1024]);
      async_cp16(vgp + vo + 8192, &Vs[cur ^ 1][w * 1024 + 512]);
      #pragma unroll
      for (int r = 0; r < 4; ++r) {
        nw0[r] = mp[r * 32 + (c + 1) * 2];
        nw1[r] = mp[r * 32 + (c + 1) * 2 + 1];
      }
    }

    f4 s[4];
    #pragma unroll
    for (int f = 0; f < 4; ++f) {
      int row = f * 16 + ln15;
      h8 bk0 = *(const h8*)&Ks[cur][row * 64 + SW(row, quad)];
      h8 bk1 = *(const h8*)&Ks[cur][row * 64 + SW(row, 4 + quad)];
      f4 acc = (f4){0.f, 0.f, 0.f, 0.f};
      acc = MF16(aq0, bk0, acc);
      acc = MF16(aq1, bk1, acc);
      s[f] = acc;
    }
    #pragma unroll
    for (int f = 0; f < 4; ++f) {
      const int col = f * 16 + ln15;
      #pragma unroll
      for (int r = 0; r < 4; ++r) {
        unsigned int wd = (col & 32) ? w1[r] : w0[r];
        float p = ((wd >> (col & 31)) & 1u)
                    ? __expf(s[f][r] * 0.125f - 3.0f) : 0.0f;
        lrow[r] += p;
        QP[w][quad * 4 + r][col] = (_Float16)p;
      }
    }
    h8 ap0 = *(h8*)&QP[w][ln15][quad * 8];
    h8 ap1 = *(h8*)&QP[w][ln15][32 + quad * 8];
    #pragma unroll
    for (int f = 0; f < 4; ++f) {
      int row = f * 16 + ln15;
      h8 bv0 = *(const h8*)&Vs[cur][row * 64 + SW(row, quad)];
      h8 bv1 = *(const h8*)&Vs[cur][row * 64 + SW(row, 4 + quad)];
      f4 o = oacc[f];
      o = MF16(ap0, bv0, o);
      o = MF16(ap1, bv1, o);
      oacc[f] = o;
    }
    if (c < 15) {
      #pragma unroll
      for (int r = 0; r < 4; ++r) { w0[r] = nw0[r]; w1[r] = nw1[r]; }
    }
    __syncthreads();
  }

  #pragma unroll
  for (int r = 0; r < 4; ++r) {
    float sm = lrow[r];
    sm += __shfl_xor(sm, 1);
    sm += __shfl_xor(sm, 2);
    sm += __shfl_xor(sm, 4);
    sm += __shfl_xor(sm, 8);
    lrow[r] = 1.0f / sm;
  }
  #pragma unroll
  for (int f = 0; f < 4; ++f)
    #pragma unroll
    for (int r = 0; r < 4; ++r)
      QP[w][quad * 4 + r][f * 16 + ln15] = (_Float16)(oacc[f][r] * lrow[r]);
  const int orow = lane >> 2, oseg = (lane & 3) * 16;
  _Float16* op = out + qkbase + (size_t)(s0 + w * 16 + orow) * 1024 + oseg;
  *(h8*)op       = *(h8*)&QP[w][orow][oseg];
  *(h8*)(op + 8) = *(h8*)&QP[w][orow][oseg + 8];
}

// ---------------------------------------------------------------------------
extern "C" void kernel_launch(void* const* d_in, const int* in_sizes, int n_in,
                              void* d_out, int out_size, void* d_ws, size_t ws_size,
                              hipStream_t stream) {
  const float* x     = (const float*)d_in[0];
  const int*   masks = (const int*)d_in[1];
  const int*   Hm    = (const int*)d_in[2];
  const int*   Bm    = (const int*)d_in[3];
  const float* fc    = (const float*)d_in[4];
  const float* fs    = (const float*)d_in[5];
  const float* wq    = (const float*)d_in[6];
  const float* wk    = (const float*)d_in[7];
  const float* wv    = (const float*)d_in[8];
  const float* wo    = (const float*)d_in[9];
  float* out = (float*)d_out;

  _Float16* xh   = (_Float16*)d_ws;          // 2M halfs
  _Float16* wqt  = xh + (1 << 21);           // 1M each
  _Float16* wkt  = wqt + (1 << 20);
  _Float16* wvt  = wkt + (1 << 20);
  _Float16* wot  = wvt + (1 << 20);
  _Float16* qhh  = wot + (1 << 20);          // 2M
  _Float16* khh  = qhh + (1 << 21);          // 2M
  _Float16* vth  = khh + (1 << 21);          // 2M
  _Float16* aoh  = vth + (1 << 21);          // 2M
  unsigned int* mpk = (unsigned int*)(aoh + (1 << 21));  // 64K words

  dim3 blk(256);
  prep<<<dim3(2304), blk, 0, stream>>>(x, wq, wk, wv, wo, masks,
                                       xh, wqt, wkt, wvt, wot, mpk);
  gemm_qkv16<<<dim3(8, 32, 3), blk, 0, stream>>>(xh, wqt, wkt, wvt,
                                                 qhh, khh, vth);
  rope_kernel<<<dim3(128, 2), blk, 0, stream>>>(qhh, khh, Hm, Bm, fc, fs);
  attn_mfma<<<dim3(512), blk, 0, stream>>>(qhh, khh, vth, mpk, aoh);
  gemm_o16<<<dim3(8, 32), blk, 0, stream>>>(aoh, wot, out);
}

// Round 10
// 158.750 us; speedup vs baseline: 1.1619x; 1.0487x over previous
//
#include <hip/hip_runtime.h>

#define SLEN 1024
#define BATCH 2
#define DEPTH 6

typedef _Float16 h8 __attribute__((ext_vector_type(8)));
typedef float    f4 __attribute__((ext_vector_type(4)));
#define MF16(a, b, c) __builtin_amdgcn_mfma_f32_16x16x32_f16(a, b, c, 0, 0, 0)

// logical chunk <-> stored chunk swizzle (8 chunks of 8 halfs per 64-half row)
#define SW(row, c) ((((c) ^ ((row) & 7))) * 8)

// async global->LDS, 16B per lane; LDS dest = wave-uniform base + lane*16
__device__ __forceinline__ void async_cp16(const _Float16* g, _Float16* l) {
  __builtin_amdgcn_global_load_lds(
      (const __attribute__((address_space(1))) void*)g,
      (__attribute__((address_space(3))) void*)l, 16, 0, 0);
}

// ---------------------------------------------------------------------------
// prep: bid 0..1023 x->fp16 ; 1024..2047 weight transpose+convert ;
//       2048..2303 mask bit-pack
// ---------------------------------------------------------------------------
__global__ __launch_bounds__(256) void prep(const float* __restrict__ x,
    const float* __restrict__ wq, const float* __restrict__ wk,
    const float* __restrict__ wv, const float* __restrict__ wo,
    const int* __restrict__ masks, _Float16* __restrict__ xh,
    _Float16* __restrict__ qt, _Float16* __restrict__ kt,
    _Float16* __restrict__ vt, _Float16* __restrict__ ot,
    unsigned int* __restrict__ mpk) {
  __shared__ _Float16 T[64][72];
  const int bid = blockIdx.x, t = threadIdx.x;
  if (bid < 1024) {
    int idx = (bid * 256 + t) * 8;
    float4 f0 = *(const float4*)(x + idx);
    float4 f1 = *(const float4*)(x + idx + 4);
    union { h8 v; _Float16 e[8]; } u;
    u.e[0] = (_Float16)f0.x; u.e[1] = (_Float16)f0.y;
    u.e[2] = (_Float16)f0.z; u.e[3] = (_Float16)f0.w;
    u.e[4] = (_Float16)f1.x; u.e[5] = (_Float16)f1.y;
    u.e[6] = (_Float16)f1.z; u.e[7] = (_Float16)f1.w;
    *(h8*)(xh + idx) = u.v;
  } else if (bid < 2048) {
    const int i = bid - 1024;
    const int wsel = i >> 8;
    const float* W = wsel == 0 ? wq : wsel == 1 ? wk : wsel == 2 ? wv : wo;
    _Float16* O = wsel == 0 ? qt : wsel == 1 ? kt : wsel == 2 ? vt : ot;
    const int k0 = ((i >> 4) & 15) * 64, n0 = (i & 15) * 64;
    const int rr = t >> 2, cs = (t & 3) * 16;
    #pragma unroll
    for (int j = 0; j < 4; ++j) {
      float4 f = *(const float4*)(W + (size_t)(k0 + rr) * 1024 + n0 + cs + j * 4);
      T[rr][cs + j * 4 + 0] = (_Float16)f.x;
      T[rr][cs + j * 4 + 1] = (_Float16)f.y;
      T[rr][cs + j * 4 + 2] = (_Float16)f.z;
      T[rr][cs + j * 4 + 3] = (_Float16)f.w;
    }
    __syncthreads();
    const int n = t >> 2, ks = (t & 3) * 16;
    union { h8 v; _Float16 e[8]; } u0, u1;
    #pragma unroll
    for (int j = 0; j < 8; ++j) { u0.e[j] = T[ks + j][n]; u1.e[j] = T[ks + 8 + j][n]; }
    *(h8*)(O + (size_t)(n0 + n) * 1024 + k0 + ks)     = u0.v;
    *(h8*)(O + (size_t)(n0 + n) * 1024 + k0 + ks + 8) = u1.v;
  } else {
    const int g = (bid - 2048) * 256 + t;
    const int row = g >> 5, w = g & 31;
    const int* m = masks + (size_t)row * 1024 + w * 32;
    unsigned int bits = 0;
    #pragma unroll
    for (int j4 = 0; j4 < 8; ++j4) {
      int4 mm = *(const int4*)(m + j4 * 4);
      if (mm.x) bits |= 1u << (j4 * 4 + 0);
      if (mm.y) bits |= 1u << (j4 * 4 + 1);
      if (mm.z) bits |= 1u << (j4 * 4 + 2);
      if (mm.w) bits |= 1u << (j4 * 4 + 3);
    }
    mpk[g] = bits;
  }
}

// ---------------------------------------------------------------------------
// fp16 MFMA GEMM, 64x128 tile, BK=64, SINGLE-buffer async-LDS staging,
// 2 barriers per K-chunk (proven r6/r9 structure). SH passed in (24.5 KB).
// Wave-tile 32x64 (acc 2x4).
// TMODE 0: plain store. TMODE 1: V-transpose store.
// TMODE 2: fused RoPE epilogue (2 threads per (row,head), vv[32], fp32 math).
// ---------------------------------------------------------------------------
template <int TMODE, typename CT>
__device__ __forceinline__ void gemm16(const _Float16* __restrict__ A,
                                       const _Float16* __restrict__ Bt,
                                       CT* __restrict__ C,
                                       const int* __restrict__ Hm,
                                       const int* __restrict__ Bm,
                                       _Float16* __restrict__ SH,
                                       const float* __restrict__ FR) {
  _Float16* As = SH;            // 4096 halfs: 64 rows x 64
  _Float16* Bs = SH + 4096;     // 8192 halfs: 128 rows x 64
  const int t    = threadIdx.x;
  const int bm   = blockIdx.y * 64, bn = blockIdx.x * 128;
  const int w    = t >> 6, lane = t & 63;
  const int ln15 = lane & 15, quad = lane >> 4;
  const int wm   = (w >> 1) * 32, wn = (w & 1) * 64;

  // staging lane map: 8 rows x 8 chunks per issue; row&7 == lane>>3
  const int srow8 = lane >> 3;
  const int sch   = (lane & 7) ^ srow8;
  const _Float16* agp = A  + (size_t)(bm + w * 16 + srow8) * 1024 + sch * 8;
  const _Float16* bgp = Bt + (size_t)(bn + w * 32 + srow8) * 1024 + sch * 8;

  f4 acc[2][4];
  #pragma unroll
  for (int i = 0; i < 2; ++i)
    #pragma unroll
    for (int j = 0; j < 4; ++j) acc[i][j] = (f4){0.f, 0.f, 0.f, 0.f};

  for (int k0 = 0; k0 < 1024; k0 += 64) {
    #pragma unroll
    for (int j = 0; j < 2; ++j)
      async_cp16(agp + k0 + j * 8192, As + w * 1024 + j * 512);
    #pragma unroll
    for (int j = 0; j < 4; ++j)
      async_cp16(bgp + k0 + j * 8192, Bs + w * 2048 + j * 512);
    __syncthreads();   // drain async stage + all waves ready
    #pragma unroll
    for (int kk = 0; kk < 8; kk += 4) {
      h8 af[2], bf[4];
      #pragma unroll
      for (int i = 0; i < 2; ++i) {
        int row = wm + i * 16 + ln15;
        af[i] = *(const h8*)&As[row * 64 + SW(row, kk + quad)];
      }
      #pragma unroll
      for (int j = 0; j < 4; ++j) {
        int row = wn + j * 16 + ln15;
        bf[j] = *(const h8*)&Bs[row * 64 + SW(row, kk + quad)];
      }
      #pragma unroll
      for (int i = 0; i < 2; ++i)
        #pragma unroll
        for (int j = 0; j < 4; ++j)
          acc[i][j] = MF16(af[i], bf[j], acc[i][j]);
    }
    __syncthreads();   // all reads done before next chunk overwrites
  }

  if (TMODE == 0) {
    #pragma unroll
    for (int i = 0; i < 2; ++i) {
      int row = bm + wm + i * 16 + quad * 4;
      #pragma unroll
      for (int r = 0; r < 4; ++r)
        #pragma unroll
        for (int j = 0; j < 4; ++j)
          C[(size_t)(row + r) * 1024 + bn + wn + j * 16 + ln15] = (CT)acc[i][j][r];
    }
  } else if (TMODE == 1) {
    #pragma unroll
    for (int i = 0; i < 2; ++i) {
      int m0 = bm + wm + i * 16 + quad * 4;
      #pragma unroll
      for (int r = 0; r < 4; ++r) {
        int m = m0 + r;
        size_t base = ((size_t)(m >> 10) * 1024) * 1024 + (m & 1023);
        #pragma unroll
        for (int j = 0; j < 4; ++j)
          C[base + (size_t)(bn + wn + j * 16 + ln15) * 1024] = (CT)acc[i][j][r];
      }
    }
  } else {
    // ---- fused RoPE epilogue ----
    // acc -> EP = SH[0:8192) as [64][128] fp16, 8-half chunks XOR-swizzled
    // by row&15. (Safe: last K-chunk barrier passed, all As/Bs reads done.)
    _Float16* EP = SH;
    #pragma unroll
    for (int i = 0; i < 2; ++i)
      #pragma unroll
      for (int j = 0; j < 4; ++j) {
        int cl = wn + j * 16 + ln15;
        #pragma unroll
        for (int r = 0; r < 4; ++r) {
          int rl = wm + i * 16 + quad * 4 + r;
          EP[rl * 128 + (((cl >> 3) ^ (rl & 15)) << 3) + (cl & 7)] =
              (_Float16)acc[i][j][r];
        }
      }
    __syncthreads();
    // 2 threads per (row, head); part p owns head dims [16p,16p+16) u [32+16p,48+16p)
    const int row = t >> 2, head = (t >> 1) & 1, p = t & 1;
    const int bs = bm + row;              // b*1024 + s (64-row tiles never straddle batch)
    const int r15 = row & 15;
    float vv[32];
    #pragma unroll
    for (int cc = 0; cc < 4; ++cc) {
      int lc = head * 8 + 2 * p + (cc & 1) + (cc >> 1) * 4;
      union { h8 v; _Float16 e[8]; } u;
      u.v = *(const h8*)&EP[row * 128 + (lc ^ r15) * 8];
      #pragma unroll
      for (int e = 0; e < 8; ++e) vv[cc * 8 + e] = (float)u.e[e];
    }
    // vv[0:16]  = head dims [16p, 16p+16)   (rot_H pairs local; rot_B re-part)
    // vv[16:32] = head dims [32+16p, 48+16p) (rot_B im-part for vv[0:16])
    #pragma unroll 1
    for (int d = 0; d < DEPTH; ++d) {
      if (Hm[d * (BATCH * SLEN) + bs] != 0) {
        #pragma unroll
        for (int jj = 0; jj < 8; ++jj) {
          int j0 = 8 * p + jj, j1 = 16 + 8 * p + jj;
          float re0 = vv[2 * jj], im0 = vv[2 * jj + 1];
          vv[2 * jj]     = re0 * FR[j0] - im0 * FR[32 + j0];
          vv[2 * jj + 1] = re0 * FR[32 + j0] + im0 * FR[j0];
          float re1 = vv[16 + 2 * jj], im1 = vv[17 + 2 * jj];
          vv[16 + 2 * jj] = re1 * FR[j1] - im1 * FR[32 + j1];
          vv[17 + 2 * jj] = re1 * FR[32 + j1] + im1 * FR[j1];
        }
      }
      if (Bm[(d * 2 + 0) * (BATCH * SLEN) + bs] != 0) {
        #pragma unroll
        for (int jj = 0; jj < 16; ++jj) {
          int j = 16 * p + jj;
          float re = vv[jj], im = vv[16 + jj];
          vv[jj]      = re * FR[j] - im * FR[32 + j];
          vv[16 + jj] = re * FR[32 + j] + im * FR[j];
        }
      }
      if (Bm[(d * 2 + 1) * (BATCH * SLEN) + bs] != 0) {
        #pragma unroll
        for (int jj = 0; jj < 16; ++jj) {
          int j = 16 * p + jj;
          float re = vv[jj], im = vv[16 + jj];
          vv[jj]      = re * FR[64 + j] - im * FR[96 + j];
          vv[16 + jj] = re * FR[96 + j] + im * FR[64 + j];
        }
      }
    }
    _Float16* dst = (_Float16*)C + (size_t)(bm + row) * 1024 + bn + head * 64;
    #pragma unroll
    for (int cc = 0; cc < 4; ++cc) {
      union { h8 v; _Float16 e[8]; } u;
      #pragma unroll
      for (int e = 0; e < 8; ++e) u.e[e] = (_Float16)vv[cc * 8 + e];
      int off = (cc < 2) ? (16 * p + cc * 8) : (32 + 16 * p + (cc - 2) * 8);
      *(h8*)(dst + off) = u.v;
    }
  }
}

__global__ __launch_bounds__(256) void gemm_qkv16(
    const _Float16* __restrict__ xh, const _Float16* __restrict__ qt,
    const _Float16* __restrict__ kt, const _Float16* __restrict__ vtw,
    _Float16* __restrict__ q, _Float16* __restrict__ k,
    _Float16* __restrict__ vth, const int* __restrict__ Hm,
    const int* __restrict__ Bm, const float* __restrict__ fc,
    const float* __restrict__ fs) {
  __shared__ _Float16 SH[12288];
  __shared__ float FR[128];    // c1|s1|c2|s2
  if (blockIdx.z != 2 && threadIdx.x < 128) {
    int g = threadIdx.x & 31;
    FR[threadIdx.x] = (threadIdx.x < 32) ? fc[32 + g]
                    : (threadIdx.x < 64) ? fs[32 + g]
                    : (threadIdx.x < 96) ? fc[64 + g] : fs[64 + g];
  }
  if (blockIdx.z == 2)
    gemm16<1, _Float16>(xh, vtw, vth, nullptr, nullptr, SH, nullptr);
  else if (blockIdx.z == 1)
    gemm16<2, _Float16>(xh, kt, k, Hm, Bm, SH, FR);
  else
    gemm16<2, _Float16>(xh, qt, q, Hm, Bm, SH, FR);
}

__global__ __launch_bounds__(256) void gemm_o16(
    const _Float16* __restrict__ A, const _Float16* __restrict__ Bt,
    float* __restrict__ C) {
  __shared__ _Float16 SH[12288];
  gemm16<0, float>(A, Bt, C, nullptr, nullptr, SH, nullptr);
}

// ---------------------------------------------------------------------------
// MFMA flash attention, double-buffered async staging, one barrier per chunk.
// Bitpacked mask (preloaded a chunk ahead); fixed-shift softmax p=exp(s/8-3).
// (round-6..9 proven version, unchanged)
// ---------------------------------------------------------------------------
__global__ __launch_bounds__(256) void attn_mfma(const _Float16* __restrict__ qh,
    const _Float16* __restrict__ kh, const _Float16* __restrict__ vth,
    const unsigned int* __restrict__ mpk, _Float16* __restrict__ out) {
  __shared__ _Float16 Ks[2][64 * 64];
  __shared__ _Float16 Vs[2][64 * 64];
  __shared__ _Float16 QP[4][16][72];

  const int t    = threadIdx.x;
  const int w    = t >> 6, lane = t & 63;
  const int ln15 = lane & 15, quad = lane >> 4;

  const int bh = blockIdx.x & 31;       // same (b,h) -> same XCD
  const int s0 = (blockIdx.x >> 5) * 64;
  const int b = bh >> 4, h = bh & 15;
  const size_t qkbase = (size_t)b * (SLEN * 1024) + h * 64;
  const size_t vbase  = ((size_t)b * 1024 + h * 64) * SLEN;

  {
    const int srow = t >> 2, sc0 = (t & 3) * 16;
    const _Float16* src = qh + qkbase + (size_t)(s0 + srow) * 1024 + sc0;
    *(h8*)&QP[w][srow & 15][sc0]     = *(const h8*)src;
    *(h8*)&QP[w][srow & 15][sc0 + 8] = *(const h8*)(src + 8);
  }
  h8 aq0 = *(h8*)&QP[w][ln15][quad * 8];
  h8 aq1 = *(h8*)&QP[w][ln15][32 + quad * 8];

  const int srow8 = lane >> 3;
  const int sch   = (lane & 7) ^ srow8;
  const _Float16* kgp = kh + qkbase + (size_t)(w * 16 + srow8) * 1024 + sch * 8;
  const _Float16* vgp = vth + vbase + (size_t)(w * 16 + srow8) * 1024 + sch * 8;

  const unsigned int* mp = mpk + ((size_t)b * SLEN + s0 + w * 16 + quad * 4) * 32;

  float lrow[4] = {1e-30f, 1e-30f, 1e-30f, 1e-30f};
  f4 oacc[4];
  #pragma unroll
  for (int f = 0; f < 4; ++f) oacc[f] = (f4){0.f, 0.f, 0.f, 0.f};

  async_cp16(kgp,        &Ks[0][w * 1024]);
  async_cp16(kgp + 8192, &Ks[0][w * 1024 + 512]);
  async_cp16(vgp,        &Vs[0][w * 1024]);
  async_cp16(vgp + 8192, &Vs[0][w * 1024 + 512]);
  unsigned int w0[4], w1[4];
  #pragma unroll
  for (int r = 0; r < 4; ++r) { w0[r] = mp[r * 32]; w1[r] = mp[r * 32 + 1]; }
  __syncthreads();

  for (int c = 0; c < 16; ++c) {
    const int cur = c & 1;
    unsigned int nw0[4], nw1[4];
    if (c < 15) {
      const size_t ko = (size_t)((c + 1) * 64) * 1024;
      const int    vo = (c + 1) * 64;
      async_cp16(kgp + ko,        &Ks[cur ^ 1][w * 1024]);
      async_cp16(kgp + ko + 8192, &Ks[cur ^ 1][w * 1024 + 512]);
      async_cp16(vgp + vo,        &Vs[cur ^ 1][w * 1024]);
      async_cp16(vgp + vo + 8192, &Vs[cur ^ 1][w * 1024 + 512]);
      #pragma unroll
      for (int r = 0; r < 4; ++r) {
        nw0[r] = mp[r * 32 + (c + 1) * 2];
        nw1[r] = mp[r * 32 + (c + 1) * 2 + 1];
      }
    }

    f4 s[4];
    #pragma unroll
    for (int f = 0; f < 4; ++f) {
      int row = f * 16 + ln15;
      h8 bk0 = *(const h8*)&Ks[cur][row * 64 + SW(row, quad)];
      h8 bk1 = *(const h8*)&Ks[cur][row * 64 + SW(row, 4 + quad)];
      f4 acc = (f4){0.f, 0.f, 0.f, 0.f};
      acc = MF16(aq0, bk0, acc);
      acc = MF16(aq1, bk1, acc);
      s[f] = acc;
    }
    #pragma unroll
    for (int f = 0; f < 4; ++f) {
      const int col = f * 16 + ln15;
      #pragma unroll
      for (int r = 0; r < 4; ++r) {
        unsigned int wd = (col & 32) ? w1[r] : w0[r];
        float p = ((wd >> (col & 31)) & 1u)
                    ? __expf(s[f][r] * 0.125f - 3.0f) : 0.0f;
        lrow[r] += p;
        QP[w][quad * 4 + r][col] = (_Float16)p;
      }
    }
    h8 ap0 = *(h8*)&QP[w][ln15][quad * 8];
    h8 ap1 = *(h8*)&QP[w][ln15][32 + quad * 8];
    #pragma unroll
    for (int f = 0; f < 4; ++f) {
      int row = f * 16 + ln15;
      h8 bv0 = *(const h8*)&Vs[cur][row * 64 + SW(row, quad)];
      h8 bv1 = *(const h8*)&Vs[cur][row * 64 + SW(row, 4 + quad)];
      f4 o = oacc[f];
      o = MF16(ap0, bv0, o);
      o = MF16(ap1, bv1, o);
      oacc[f] = o;
    }
    if (c < 15) {
      #pragma unroll
      for (int r = 0; r < 4; ++r) { w0[r] = nw0[r]; w1[r] = nw1[r]; }
    }
    __syncthreads();
  }

  #pragma unroll
  for (int r = 0; r < 4; ++r) {
    float sm = lrow[r];
    sm += __shfl_xor(sm, 1);
    sm += __shfl_xor(sm, 2);
    sm += __shfl_xor(sm, 4);
    sm += __shfl_xor(sm, 8);
    lrow[r] = 1.0f / sm;
  }
  #pragma unroll
  for (int f = 0; f < 4; ++f)
    #pragma unroll
    for (int r = 0; r < 4; ++r)
      QP[w][quad * 4 + r][f * 16 + ln15] = (_Float16)(oacc[f][r] * lrow[r]);
  const int orow = lane >> 2, oseg = (lane & 3) * 16;
  _Float16* op = out + qkbase + (size_t)(s0 + w * 16 + orow) * 1024 + oseg;
  *(h8*)op       = *(h8*)&QP[w][orow][oseg];
  *(h8*)(op + 8) = *(h8*)&QP[w][orow][oseg + 8];
}

// ---------------------------------------------------------------------------
extern "C" void kernel_launch(void* const* d_in, const int* in_sizes, int n_in,
                              void* d_out, int out_size, void* d_ws, size_t ws_size,
                              hipStream_t stream) {
  const float* x     = (const float*)d_in[0];
  const int*   masks = (const int*)d_in[1];
  const int*   Hm    = (const int*)d_in[2];
  const int*   Bm    = (const int*)d_in[3];
  const float* fc    = (const float*)d_in[4];
  const float* fs    = (const float*)d_in[5];
  const float* wq    = (const float*)d_in[6];
  const float* wk    = (const float*)d_in[7];
  const float* wv    = (const float*)d_in[8];
  const float* wo    = (const float*)d_in[9];
  float* out = (float*)d_out;

  _Float16* xh   = (_Float16*)d_ws;          // 2M halfs
  _Float16* wqt  = xh + (1 << 21);           // 1M each
  _Float16* wkt  = wqt + (1 << 20);
  _Float16* wvt  = wkt + (1 << 20);
  _Float16* wot  = wvt + (1 << 20);
  _Float16* qhh  = wot + (1 << 20);          // 2M
  _Float16* khh  = qhh + (1 << 21);          // 2M
  _Float16* vth  = khh + (1 << 21);          // 2M
  _Float16* aoh  = vth + (1 << 21);          // 2M
  unsigned int* mpk = (unsigned int*)(aoh + (1 << 21));  // 64K words

  dim3 blk(256);
  prep<<<dim3(2304), blk, 0, stream>>>(x, wq, wk, wv, wo, masks,
                                       xh, wqt, wkt, wvt, wot, mpk);
  gemm_qkv16<<<dim3(8, 32, 3), blk, 0, stream>>>(xh, wqt, wkt, wvt,
                                                 qhh, khh, vth, Hm, Bm, fc, fs);
  attn_mfma<<<dim3(512), blk, 0, stream>>>(qhh, khh, vth, mpk, aoh);
  gemm_o16<<<dim3(8, 32), blk, 0, stream>>>(aoh, wot, out);
}